// Round 2
// baseline (218.762 us; speedup 1.0000x reference)
//
#include <hip/hip_runtime.h>
#include <cstdint>

#define N_ROWS 32768
#define KDIM 1024
#define DDIM 256

typedef __attribute__((ext_vector_type(8))) short bf16x8;
typedef __attribute__((ext_vector_type(4))) float f32x4;

__device__ __forceinline__ unsigned short f2bf(float f) {
  unsigned int u = __float_as_uint(f);
  u += 0x7FFFu + ((u >> 16) & 1u);
  return (unsigned short)(u >> 16);
}

// async global->LDS, 16B per lane. LDS dest = wave-uniform base + lane*16.
__device__ __forceinline__ void gload_lds16(const void* g, void* l) {
  __builtin_amdgcn_global_load_lds(
      (const __attribute__((address_space(1))) unsigned int*)(uintptr_t)g,
      (__attribute__((address_space(3))) unsigned int*)(unsigned int)(uintptr_t)l,
      16, 0, 0);
}

// Global layouts (u16 offsets), XOR chunk swizzle baked in (chunk = 8 u16 = 16 B):
// Cn64 [t=c>>6][kb=d>>5][c&63][32]: off = t*16384 + kb*2048 + (c&63)*32 + ((((d&31)>>3)^(c&3))*8) + (d&7)
// CnT  [s=c>>5][d][32]:            off = s*8192 + d*32 + ((((c&31)>>3)^(d&3))*8) + (c&7)
// Fragment reads use chunk = l4 ^ (l15&3) -> 2-way bank aliasing only (free).

// ---------------- fully fused kernel: cb-norm + grid spin-barrier + pass A/B + loss.
// 256 blocks x 512 thr, 152 KB LDS -> exactly 1 block/CU, all 256 resident (spin is safe).
// Counted-vmcnt barriers (T4): loads stay in flight across s_barrier; no vmcnt(0) drains
// inside the two hot loops.
__global__ __launch_bounds__(512, 2) void k_fused(const float* __restrict__ x,
                                                  const float* __restrict__ cb,
                                                  unsigned short* __restrict__ Cn,
                                                  unsigned short* __restrict__ CnT,
                                                  float* __restrict__ colsum_g,
                                                  float* __restrict__ accL,
                                                  int* __restrict__ cnt1,
                                                  int* __restrict__ cnt2,
                                                  float* __restrict__ out) {
  __shared__ unsigned short Cb[4][16384];   // 128 KB ring; Cb[0..1] doubles as Xs transient
  __shared__ unsigned short Ps[128 * 72];   // 18 KB, stride 72 (16B-aligned, bank-spread)
  __shared__ float csl[1024];
  __shared__ float rs[128], qs[128], irl[128];
  __shared__ float lse_sh[2];
  __shared__ float sh1[4], sh2[4];
  __shared__ int lastf;

  const int tid = threadIdx.x, wid = tid >> 6, lane = tid & 63;
  const int l15 = lane & 15, l4 = lane >> 4;
  const int wm = wid >> 1, wn = wid & 1;  // wave: 32 rows x (32 cols S / 128 d PV)
  const int rb = blockIdx.x;              // 256 blocks x 128 rows
  if (tid < 128) { rs[tid] = 0.f; qs[tid] = 0.f; }
  for (int j = tid; j < 1024; j += 512) csl[j] = 0.f;

  // ---- cb norm: 4 codes per block (waves 0-3), written to global swizzled layouts
  if (wid < 4) {
    const int k = rb * 4 + wid;
    float4 v = ((const float4*)(cb + (size_t)k * DDIM))[lane];
    float s = v.x * v.x + v.y * v.y + v.z * v.z + v.w * v.w;
#pragma unroll
    for (int m = 32; m; m >>= 1) s += __shfl_xor(s, m, 64);
    const float rn = 1.0f / sqrtf(s);
    ushort4 p;
    p.x = f2bf(v.x * rn); p.y = f2bf(v.y * rn);
    p.z = f2bf(v.z * rn); p.w = f2bf(v.w * rn);
    const int kb = lane >> 3;
    const int physA = ((lane & 7) >> 1) ^ (k & 3);
    *(ushort4*)(Cn + (size_t)(k >> 6) * 16384 + kb * 2048 + (k & 63) * 32 + physA * 8 + (lane & 1) * 4) = p;
    const int sgl = k >> 5, c31 = k & 31, ch = c31 >> 3, cw = c31 & 7;
    const unsigned short pv[4] = {p.x, p.y, p.z, p.w};
#pragma unroll
    for (int j = 0; j < 4; ++j) {
      const int d = lane * 4 + j;
      CnT[(size_t)sgl * 8192 + d * 32 + ((ch ^ j) * 8) + cw] = pv[j];
    }
  }

  // ---- x norm: one wave per row, 16 passes -> Xs (= Cb[0..1] region, plain layout)
  unsigned short* Xs = &Cb[0][0];
#pragma unroll
  for (int p16 = 0; p16 < 16; ++p16) {
    const int row = p16 * 8 + wid;
    float4 v = ((const float4*)(x + (size_t)(rb * 128 + row) * DDIM))[lane];
    float s = v.x * v.x + v.y * v.y + v.z * v.z + v.w * v.w;
#pragma unroll
    for (int m = 32; m; m >>= 1) s += __shfl_xor(s, m, 64);
    const float rn = 1.0f / sqrtf(s);
    ushort4 p;
    p.x = f2bf(v.x * rn); p.y = f2bf(v.y * rn);
    p.z = f2bf(v.z * rn); p.w = f2bf(v.w * rn);
    *(ushort4*)&Xs[(lane >> 3) * 4096 + row * 32 + (lane & 7) * 4] = p;
  }

  // ---- grid barrier: release our cb writes, spin until all 256 blocks released.
  __syncthreads();       // all cb/x stores complete to L2 (vmcnt 0 drain), Xs visible
  __threadfence();       // write-back this XCD's L2 (release)
  if (tid == 0) {
    __hip_atomic_fetch_add(cnt1, 1, __ATOMIC_RELEASE, __HIP_MEMORY_SCOPE_AGENT);
    while (__hip_atomic_load(cnt1, __ATOMIC_ACQUIRE, __HIP_MEMORY_SCOPE_AGENT) < 256)
      __builtin_amdgcn_s_sleep(2);   // acquire: invalidates this CU's L1 + XCD L2
  }
  __syncthreads();       // cb ready device-wide; clean vmcnt queue for counted waits

  // ---- prologue stages: Cn tile0 -> slot2, tile1 -> slot3 (t0's 4 loads BEFORE t1's 4)
#pragma unroll
  for (int i = 0; i < 4; ++i) {
    const int off = i * 8192 + wid * 1024 + lane * 16;
    gload_lds16((const char*)Cn + off, (char*)Cb[2] + off);
  }
#pragma unroll
  for (int i = 0; i < 4; ++i) {
    const int off = i * 8192 + wid * 1024 + lane * 16;
    gload_lds16((const char*)Cn + 32768 + off, (char*)Cb[3] + off);
  }

  // A-fragments -> registers (one-time; Xs region is then recycled by the ring)
  bf16x8 areg[2][8];
#pragma unroll
  for (int mi = 0; mi < 2; ++mi)
#pragma unroll
    for (int kb = 0; kb < 8; ++kb)
      areg[mi][kb] = *(const bf16x8*)&Xs[kb * 4096 + (wm * 32 + mi * 16 + l15) * 32 + l4 * 8];
  asm volatile("s_waitcnt lgkmcnt(0)" ::: "memory");  // areg in regs before slot0/1 rewrite
  __builtin_amdgcn_s_barrier();

  const int xsw = l4 ^ (l15 & 3);

  // ---------------- Pass A: r, q (counted vmcnt(8), 1 non-draining barrier/kt) ----------------
  float se[2][4], sq[2][4];
#pragma unroll
  for (int mi = 0; mi < 2; ++mi)
#pragma unroll
    for (int reg = 0; reg < 4; ++reg) { se[mi][reg] = 0.f; sq[mi][reg] = 0.f; }
  for (int kt = 0; kt < 16; ++kt) {
    // issue stage(kt+2) -> slot kt&3 (tails: pass-B Cn t0, CnT t0)
    {
      const char* src = (kt <= 13) ? (const char*)Cn + (size_t)(kt + 2) * 32768
                      : (kt == 14) ? (const char*)Cn
                                   : (const char*)CnT;
      char* dst = (char*)Cb[kt & 3];
#pragma unroll
      for (int i = 0; i < 4; ++i) {
        const int off = i * 8192 + wid * 1024 + lane * 16;
        gload_lds16(src + off, dst + off);
      }
    }
    // in flight: stage(kt) 4 + stage(kt+1) 4 + stage(kt+2) 4; need stage(kt) -> vmcnt(8)
    asm volatile("s_waitcnt vmcnt(8)" ::: "memory");
    __builtin_amdgcn_s_barrier();   // all threads' stage(kt) landed; slot-reuse ordered
    const unsigned short* B = Cb[(kt + 2) & 3];
    f32x4 acc[2][2] = {};
#pragma unroll
    for (int kb = 0; kb < 8; ++kb) {
      bf16x8 b[2];
#pragma unroll
      for (int ni = 0; ni < 2; ++ni)
        b[ni] = *(const bf16x8*)&B[kb * 2048 + (wn * 32 + ni * 16 + l15) * 32 + xsw * 8];
#pragma unroll
      for (int mi = 0; mi < 2; ++mi)
#pragma unroll
        for (int ni = 0; ni < 2; ++ni)
          acc[mi][ni] = __builtin_amdgcn_mfma_f32_16x16x32_bf16(areg[mi][kb], b[ni], acc[mi][ni], 0, 0, 0);
    }
#pragma unroll
    for (int mi = 0; mi < 2; ++mi)
#pragma unroll
      for (int reg = 0; reg < 4; ++reg)
#pragma unroll
        for (int ni = 0; ni < 2; ++ni) {
          const float e = __expf(acc[mi][ni][reg]);
          se[mi][reg] += e; sq[mi][reg] += e * e;
        }
  }
#pragma unroll
  for (int mi = 0; mi < 2; ++mi)
#pragma unroll
    for (int reg = 0; reg < 4; ++reg) {
#pragma unroll
      for (int m = 1; m < 16; m <<= 1) {
        se[mi][reg] += __shfl_xor(se[mi][reg], m, 64);
        sq[mi][reg] += __shfl_xor(sq[mi][reg], m, 64);
      }
    }
  if (l15 == 0) {
#pragma unroll
    for (int mi = 0; mi < 2; ++mi)
#pragma unroll
      for (int reg = 0; reg < 4; ++reg) {
        const int row = wm * 32 + mi * 16 + l4 * 4 + reg;
        atomicAdd(&rs[row], se[mi][reg]);
        atomicAdd(&qs[row], sq[mi][reg]);
      }
  }
  __syncthreads();  // full drain OK here (once): also lands pass-B t0 stages in slots 2,3
  if (tid < 128) {
    const float r = rs[tid];
    const float irv = 1.0f / r;
    irl[tid] = irv;
    // series-LSE: sum_k exp(e_k/r) = K + 1 + q/(2 r^2)  (|d|~1e-3, err ~1e-9)
    float lse = logf((float)(KDIM + 1) + 0.5f * qs[tid] * irv * irv);
#pragma unroll
    for (int m = 32; m; m >>= 1) lse += __shfl_xor(lse, m, 64);
    if ((tid & 63) == 0) lse_sh[tid >> 6] = lse;
  }
  __syncthreads();
  if (tid == 0) atomicAdd(accL, lse_sh[0] + lse_sh[1]);
  float ir[2][4];
#pragma unroll
  for (int mi = 0; mi < 2; ++mi)
#pragma unroll
    for (int reg = 0; reg < 4; ++reg)
      ir[mi][reg] = irl[wm * 32 + mi * 16 + l4 * 4 + reg];

  // ---------------- Pass B: recompute S, colsum, PV (counted vmcnt(4), 2 barriers/kt) ----------------
  f32x4 O[2][8] = {};
  const int psw_r = l15 >> 1;
  for (int kt = 0; kt < 16; ++kt) {
    const int cslot = (kt & 1) ? 0 : 2;   // Cn(kt)
    const int tslot = cslot | 1;          // CnT(kt)
    const int nslot = (kt & 1) ? 2 : 0;   // target pair for kt+1
    const int nt = (kt < 15) ? kt + 1 : 15;  // clamped tail re-stage keeps waits uniform
    // p1: issue Cn(nt) -> Cb[nslot]
#pragma unroll
    for (int i = 0; i < 4; ++i) {
      const int off = i * 8192 + wid * 1024 + lane * 16;
      gload_lds16((const char*)Cn + (size_t)nt * 32768 + off, (char*)Cb[nslot] + off);
    }
    // S on Cb[cslot] (landed: waited + barriered at end of kt-1)
    f32x4 S[2][2] = {};
#pragma unroll
    for (int kb = 0; kb < 8; ++kb) {
      bf16x8 b[2];
#pragma unroll
      for (int ni = 0; ni < 2; ++ni)
        b[ni] = *(const bf16x8*)&Cb[cslot][kb * 2048 + (wn * 32 + ni * 16 + l15) * 32 + xsw * 8];
#pragma unroll
      for (int mi = 0; mi < 2; ++mi)
#pragma unroll
        for (int ni = 0; ni < 2; ++ni)
          S[mi][ni] = __builtin_amdgcn_mfma_f32_16x16x32_bf16(areg[mi][kb], b[ni], S[mi][ni], 0, 0, 0);
    }
    // epilogue: exp -> Ps (stride 72, swizzled); colsum partials
    float cs[2] = {0.f, 0.f};
#pragma unroll
    for (int mi = 0; mi < 2; ++mi)
#pragma unroll
      for (int reg = 0; reg < 4; ++reg) {
        const int row = wm * 32 + mi * 16 + l4 * 4 + reg;
        const int pswz = (l4 * 2 + (reg >> 1)) & 7;  // ((row&15)>>1)
#pragma unroll
        for (int ni = 0; ni < 2; ++ni) {
          const float e = __expf(S[mi][ni][reg]);
          const int chl = wn * 4 + ni * 2 + (l15 >> 3);
          Ps[row * 72 + ((chl ^ pswz) * 8) + (l15 & 7)] = f2bf(e);
          cs[ni] += e * ir[mi][reg];
        }
      }
#pragma unroll
    for (int ni = 0; ni < 2; ++ni) {
      float v = cs[ni];
      v += __shfl_xor(v, 16, 64);
      v += __shfl_xor(v, 32, 64);
      if (lane < 16) atomicAdd(&csl[kt * 64 + wn * 32 + ni * 16 + l15], v);
    }
    // B1: Ps visible (lgkm) + CnT(kt) landed (vmcnt: in-flight = T(kt) 4 + Cn(nt) 4 -> keep 4)
    asm volatile("s_waitcnt vmcnt(4) lgkmcnt(0)" ::: "memory");
    __builtin_amdgcn_s_barrier();
    __builtin_amdgcn_sched_barrier(0);
    // issue CnT(nt) -> Cb[nslot+1] (lives across B2)
#pragma unroll
    for (int i = 0; i < 4; ++i) {
      const int off = i * 8192 + wid * 1024 + lane * 16;
      gload_lds16((const char*)CnT + (size_t)nt * 32768 + off, (char*)Cb[nslot + 1] + off);
    }
    // PV: O += Ps @ CnT
#pragma unroll
    for (int kb2 = 0; kb2 < 2; ++kb2) {
      bf16x8 a2[2], b2[8];
#pragma unroll
      for (int mi = 0; mi < 2; ++mi) {
        const int row = wm * 32 + mi * 16 + l15;
        a2[mi] = *(const bf16x8*)&Ps[row * 72 + (((kb2 * 4 + l4) ^ psw_r) * 8)];
      }
#pragma unroll
      for (int ni = 0; ni < 8; ++ni) {
        const int d = wn * 128 + ni * 16 + l15;
        b2[ni] = *(const bf16x8*)&Cb[tslot][kb2 * 8192 + d * 32 + xsw * 8];
      }
#pragma unroll
      for (int mi = 0; mi < 2; ++mi)
#pragma unroll
        for (int ni = 0; ni < 8; ++ni)
          O[mi][ni] = __builtin_amdgcn_mfma_f32_16x16x32_bf16(a2[mi], b2[ni], O[mi][ni], 0, 0, 0);
    }
    // B2: Cn(nt) landed (in-flight = Cn(nt) 4 + T(nt) 4 -> keep 4); Ps reads already in regs
    asm volatile("s_waitcnt vmcnt(4)" ::: "memory");
    __builtin_amdgcn_s_barrier();
  }
  __syncthreads();  // drain clamped tail stages; csl fully visible

  // out = O * ir
#pragma unroll
  for (int mi = 0; mi < 2; ++mi)
#pragma unroll
    for (int reg = 0; reg < 4; ++reg) {
      const int row = wm * 32 + mi * 16 + l4 * 4 + reg;
      const float irv = ir[mi][reg];
#pragma unroll
      for (int ni = 0; ni < 8; ++ni) {
        const int d = wn * 128 + ni * 16 + l15;
        out[(size_t)(rb * 128 + row) * DDIM + d] = O[mi][ni][reg] * irv;
      }
    }
  // colsum partials -> global atomics
  for (int j = tid; j < 1024; j += 512) atomicAdd(&colsum_g[j], csl[j]);

  // ---- last block computes the loss (ticket via cnt2)
  if (tid == 0) {
    __threadfence();
    const int old = __hip_atomic_fetch_add(cnt2, 1, __ATOMIC_ACQ_REL, __HIP_MEMORY_SCOPE_AGENT);
    lastf = (old == 255);
  }
  __syncthreads();
  if (lastf) {
    if (tid < 256) {
      float s = 0.f, q = 0.f;
#pragma unroll
      for (int j = 0; j < 4; ++j) {
        const float c = __hip_atomic_load(&colsum_g[tid + j * 256], __ATOMIC_RELAXED, __HIP_MEMORY_SCOPE_AGENT);
        s += c; q += c * c;
      }
#pragma unroll
      for (int m = 1; m < 64; m <<= 1) {
        s += __shfl_xor(s, m, 64);
        q += __shfl_xor(q, m, 64);
      }
      if (lane == 0) { sh1[tid >> 6] = s; sh2[tid >> 6] = q; }
    }
    __syncthreads();
    if (tid == 0) {
      const double S = (double)sh1[0] + sh1[1] + sh1[2] + sh1[3];  // sum of all distances (~N)
      const double Q = (double)sh2[0] + sh2[1] + sh2[2] + sh2[3];  // ||colsum||^2
      const double L = __hip_atomic_load(accL, __ATOMIC_RELAXED, __HIP_MEMORY_SCOPE_AGENT);
      const double entropy = (S * L - Q) / (double)N_ROWS;
      const double l1 = S / ((double)N_ROWS * (double)KDIM);
      out[(size_t)N_ROWS * DDIM] = (float)(1000.0 * l1 + 5e-5 * entropy);
    }
  }
}

extern "C" void kernel_launch(void* const* d_in, const int* in_sizes, int n_in,
                              void* d_out, int out_size, void* d_ws, size_t ws_size,
                              hipStream_t stream) {
  const float* x = (const float*)d_in[0];   // [8,4096,256] fp32
  const float* cb = (const float*)d_in[1];  // [1024,256] fp32
  float* out = (float*)d_out;               // recon [8388608] + loss [1]
  char* ws = (char*)d_ws;

  unsigned short* Cn  = (unsigned short*)(ws + 0);         // 524288 B (Cn64 swizzled)
  unsigned short* CnT = (unsigned short*)(ws + 524288);    // 524288 B (CnT swizzled)
  float* colsum_g     = (float*)(ws + 1048576);            // 4096 B
  float* accL         = (float*)(ws + 1052672);            // 4 B
  int* cnt1           = (int*)(ws + 1052676);              // 4 B (grid barrier)
  int* cnt2           = (int*)(ws + 1052680);              // 4 B (loss ticket)

  hipMemsetAsync(ws + 1048576, 0, 4112, stream);
  k_fused<<<256, 512, 0, stream>>>(x, cb, Cn, CnT, colsum_g, accL, cnt1, cnt2, out);
}

// Round 3
// 169.459 us; speedup vs baseline: 1.2909x; 1.2909x over previous
//
#include <hip/hip_runtime.h>
#include <cstdint>

#define N_ROWS 32768
#define KDIM 1024
#define DDIM 256

typedef __attribute__((ext_vector_type(8))) short bf16x8;
typedef __attribute__((ext_vector_type(4))) float f32x4;

__device__ __forceinline__ unsigned short f2bf(float f) {
  unsigned int u = __float_as_uint(f);
  u += 0x7FFFu + ((u >> 16) & 1u);
  return (unsigned short)(u >> 16);
}

// async global->LDS, 16B per lane. LDS dest = wave-uniform base + lane*16.
__device__ __forceinline__ void gload_lds16(const void* g, void* l) {
  __builtin_amdgcn_global_load_lds(
      (const __attribute__((address_space(1))) unsigned int*)(uintptr_t)g,
      (__attribute__((address_space(3))) unsigned int*)(unsigned int)(uintptr_t)l,
      16, 0, 0);
}

// Global layouts (u16 offsets), XOR chunk swizzle baked in (chunk = 8 u16 = 16 B):
// Cn64 [t=c>>6][kb=d>>5][c&63][32]: off = t*16384 + kb*2048 + (c&63)*32 + ((((d&31)>>3)^(c&3))*8) + (d&7)
// CnT  [s=c>>5][d][32]:            off = s*8192 + d*32 + ((((c&31)>>3)^(d&3))*8) + (c&7)
// Fragment reads use chunk = l4 ^ (l15&3) -> 2-way bank aliasing only (free).

// ---------------- normalize codebook -> Cn64, CnT (bf16, swizzled)
__global__ __launch_bounds__(256) void k_norm_cb(const float* __restrict__ cb,
                                                 unsigned short* __restrict__ Cn,
                                                 unsigned short* __restrict__ CnT) {
  const int wid = threadIdx.x >> 6, lane = threadIdx.x & 63;
  const int k = blockIdx.x * 4 + wid;  // 1024 codes
  float4 v = ((const float4*)(cb + (size_t)k * DDIM))[lane];
  float s = v.x * v.x + v.y * v.y + v.z * v.z + v.w * v.w;
#pragma unroll
  for (int m = 32; m; m >>= 1) s += __shfl_xor(s, m, 64);
  const float rn = 1.0f / sqrtf(s);
  ushort4 p;
  p.x = f2bf(v.x * rn); p.y = f2bf(v.y * rn);
  p.z = f2bf(v.z * rn); p.w = f2bf(v.w * rn);
  const int kb = lane >> 3;
  const int physA = ((lane & 7) >> 1) ^ (k & 3);
  *(ushort4*)(Cn + (size_t)(k >> 6) * 16384 + kb * 2048 + (k & 63) * 32 + physA * 8 + (lane & 1) * 4) = p;
  const int sgl = k >> 5, c31 = k & 31, ch = c31 >> 3, cw = c31 & 7;
  const unsigned short pv[4] = {p.x, p.y, p.z, p.w};
#pragma unroll
  for (int j = 0; j < 4; ++j) {
    const int d = lane * 4 + j;
    CnT[(size_t)sgl * 8192 + d * 32 + ((ch ^ j) * 8) + cw] = pv[j];
  }
}

// ---------------- k_all: one block = 128 rows, 256 blocks (1/CU).
// Wave map: 8 waves = 2 row-groups (wm, 64 rows) x 4 col-groups (wn).
// M=64/wave halves the B-fragment LDS read amplification (4x -> 2x) vs the
// old 4x2 map; areg doubles to 128 VGPR (budget 256 at the forced 2 waves/SIMD).
// Round-0 4-slot ring + plain __syncthreads (counted-vmcnt measured null: LDS-BW-bound).
// Final reduction folded in via last-block ticket (no grid barrier!).
__global__ __launch_bounds__(512, 2) void k_all(const float* __restrict__ x,
                                                const unsigned short* __restrict__ Cn,
                                                const unsigned short* __restrict__ CnT,
                                                float* __restrict__ colsum_g,
                                                float* __restrict__ accL,
                                                int* __restrict__ cnt2,
                                                float* __restrict__ out) {
  __shared__ unsigned short Cb[4][16384];   // 128 KB ring; Cb[0..1] doubles as Xs transient
  __shared__ unsigned short Ps[128 * 72];   // 18 KB, stride 72 (16B-aligned, bank-spread)
  __shared__ float csl[1024];
  __shared__ float rs[128], qs[128], irl[128];
  __shared__ float lse_sh[2];
  __shared__ float sh1[4], sh2[4];
  __shared__ int lastf;

  const int tid = threadIdx.x, wid = tid >> 6, lane = tid & 63;
  const int l15 = lane & 15, l4 = lane >> 4;
  const int wm = wid >> 2, wn = wid & 3;  // wave: 64 rows x (16 cols S / 64 d PV)
  const int rb = blockIdx.x;              // 256 blocks x 128 rows
  if (tid < 128) { rs[tid] = 0.f; qs[tid] = 0.f; }
  for (int j = tid; j < 1024; j += 512) csl[j] = 0.f;

  // early stage: Cn[0]->Cb[2], Cn[1]->Cb[3] (overlaps norm phase)
#pragma unroll
  for (int i = 0; i < 4; ++i) {
    const int off = i * 8192 + wid * 1024 + lane * 16;
    gload_lds16((const char*)Cn + off, (char*)Cb[2] + off);
    gload_lds16((const char*)Cn + 32768 + off, (char*)Cb[3] + off);
  }

  // norm: one wave per row, 16 passes -> Xs (= Cb[0..1] region, plain layout)
  unsigned short* Xs = &Cb[0][0];
#pragma unroll
  for (int p16 = 0; p16 < 16; ++p16) {
    const int row = p16 * 8 + wid;
    float4 v = ((const float4*)(x + (size_t)(rb * 128 + row) * DDIM))[lane];
    float s = v.x * v.x + v.y * v.y + v.z * v.z + v.w * v.w;
#pragma unroll
    for (int m = 32; m; m >>= 1) s += __shfl_xor(s, m, 64);
    const float rn = 1.0f / sqrtf(s);
    ushort4 p;
    p.x = f2bf(v.x * rn); p.y = f2bf(v.y * rn);
    p.z = f2bf(v.z * rn); p.w = f2bf(v.w * rn);
    *(ushort4*)&Xs[(lane >> 3) * 4096 + row * 32 + (lane & 7) * 4] = p;
  }
  __syncthreads();
  // A-fragments -> registers: 64 rows/wave (4 mi), one-time; Xs then recycled by ring
  bf16x8 areg[4][8];
#pragma unroll
  for (int mi = 0; mi < 4; ++mi)
#pragma unroll
    for (int kb = 0; kb < 8; ++kb)
      areg[mi][kb] = *(const bf16x8*)&Xs[kb * 4096 + (wm * 64 + mi * 16 + l15) * 32 + l4 * 8];

  const int xsw = l4 ^ (l15 & 3);

  // ---------------- Pass A: r, q ----------------
  float se[4][4], sq[4][4];
#pragma unroll
  for (int mi = 0; mi < 4; ++mi)
#pragma unroll
    for (int reg = 0; reg < 4; ++reg) { se[mi][reg] = 0.f; sq[mi][reg] = 0.f; }
  for (int kt = 0; kt < 16; ++kt) {
    __syncthreads();  // stage(kt) complete; areg reads done (kt=0); ring reuse safe
    // issue prefetch for kt+2 (tail: Cn[0], CnT[0] for pass B)
    {
      const char* src = (kt <= 13) ? (const char*)Cn + (size_t)(kt + 2) * 32768
                      : (kt == 14) ? (const char*)Cn
                                   : (const char*)CnT;
      char* dst = (char*)Cb[kt & 3];
#pragma unroll
      for (int i = 0; i < 4; ++i) {
        const int off = i * 8192 + wid * 1024 + lane * 16;
        gload_lds16(src + off, dst + off);
      }
    }
    const unsigned short* B = Cb[(kt + 2) & 3];
    f32x4 acc[4] = {};
#pragma unroll
    for (int kb = 0; kb < 8; ++kb) {
      bf16x8 b = *(const bf16x8*)&B[kb * 2048 + (wn * 16 + l15) * 32 + xsw * 8];
#pragma unroll
      for (int mi = 0; mi < 4; ++mi)
        acc[mi] = __builtin_amdgcn_mfma_f32_16x16x32_bf16(areg[mi][kb], b, acc[mi], 0, 0, 0);
    }
#pragma unroll
    for (int mi = 0; mi < 4; ++mi)
#pragma unroll
      for (int reg = 0; reg < 4; ++reg) {
        const float e = __expf(acc[mi][reg]);
        se[mi][reg] += e; sq[mi][reg] += e * e;
      }
  }
#pragma unroll
  for (int mi = 0; mi < 4; ++mi)
#pragma unroll
    for (int reg = 0; reg < 4; ++reg) {
#pragma unroll
      for (int m = 1; m < 16; m <<= 1) {
        se[mi][reg] += __shfl_xor(se[mi][reg], m, 64);
        sq[mi][reg] += __shfl_xor(sq[mi][reg], m, 64);
      }
    }
  if (l15 == 0) {
#pragma unroll
    for (int mi = 0; mi < 4; ++mi)
#pragma unroll
      for (int reg = 0; reg < 4; ++reg) {
        const int row = wm * 64 + mi * 16 + l4 * 4 + reg;
        atomicAdd(&rs[row], se[mi][reg]);
        atomicAdd(&qs[row], sq[mi][reg]);
      }
  }
  __syncthreads();  // also drains pass-A tail stages (Cn[0],CnT[0])
  if (tid < 128) {
    const float r = rs[tid];
    const float irv = 1.0f / r;
    irl[tid] = irv;
    // series-LSE: sum_k exp(e_k/r) = K + 1 + q/(2 r^2)  (|d|~1e-3, err ~1e-9)
    float lse = logf((float)(KDIM + 1) + 0.5f * qs[tid] * irv * irv);
#pragma unroll
    for (int m = 32; m; m >>= 1) lse += __shfl_xor(lse, m, 64);
    if ((tid & 63) == 0) lse_sh[tid >> 6] = lse;
  }
  __syncthreads();
  if (tid == 0) atomicAdd(accL, lse_sh[0] + lse_sh[1]);
  f32x4 ir[4];  // ir[mi][reg] = irl[wm*64+mi*16+l4*4+reg] (vector read, broadcast across l15)
#pragma unroll
  for (int mi = 0; mi < 4; ++mi)
    ir[mi] = *(const f32x4*)&irl[wm * 64 + mi * 16 + l4 * 4];

  // ---------------- Pass B: recompute S, colsum, PV ----------------
  f32x4 O[4][4] = {};
  const int psw_r = l15 >> 1;
  for (int kt = 0; kt < 16; ++kt) {
    const int cslot = (kt & 1) ? 0 : 2;   // Cn(kt)
    const int tslot = cslot | 1;          // CnT(kt)
    const int nslot = (kt & 1) ? 2 : 0;   // target pair for kt+1
    if (kt < 15) {  // stage Cn[kt+1] (full S window to complete)
#pragma unroll
      for (int i = 0; i < 4; ++i) {
        const int off = i * 8192 + wid * 1024 + lane * 16;
        gload_lds16((const char*)Cn + (size_t)(kt + 1) * 32768 + off, (char*)Cb[nslot] + off);
      }
    }
    f32x4 S[4] = {};
#pragma unroll
    for (int kb = 0; kb < 8; ++kb) {
      bf16x8 b = *(const bf16x8*)&Cb[cslot][kb * 2048 + (wn * 16 + l15) * 32 + xsw * 8];
#pragma unroll
      for (int mi = 0; mi < 4; ++mi)
        S[mi] = __builtin_amdgcn_mfma_f32_16x16x32_bf16(areg[mi][kb], b, S[mi], 0, 0, 0);
    }
    // epilogue: exp -> Ps (stride 72, swizzled); colsum partials
    const int chl = wn * 2 + (l15 >> 3);
    float cs = 0.f;
#pragma unroll
    for (int mi = 0; mi < 4; ++mi)
#pragma unroll
      for (int reg = 0; reg < 4; ++reg) {
        const int row = wm * 64 + mi * 16 + l4 * 4 + reg;
        const int pswz = (l4 * 2 + (reg >> 1)) & 7;  // ((row&15)>>1)
        const float e = __expf(S[mi][reg]);
        Ps[row * 72 + ((chl ^ pswz) * 8) + (l15 & 7)] = f2bf(e);
        cs += e * ir[mi][reg];
      }
    // reduce cs over l4 -> full 64-row sum for code wn*16+l15
    cs += __shfl_xor(cs, 16, 64);
    cs += __shfl_xor(cs, 32, 64);
    if (lane < 16) atomicAdd(&csl[kt * 64 + wn * 16 + l15], cs);
    __syncthreads();  // Ps visible; Cn[kt+1] drained (had S window)
    if (kt < 15) {  // stage CnT[kt+1] (PV window to complete)
#pragma unroll
      for (int i = 0; i < 4; ++i) {
        const int off = i * 8192 + wid * 1024 + lane * 16;
        gload_lds16((const char*)CnT + (size_t)(kt + 1) * 32768 + off, (char*)Cb[nslot + 1] + off);
      }
    }
    // PV: O += Ps @ CnT   (per kb2: a2[0..3] then stream b2 one ni at a time)
#pragma unroll
    for (int kb2 = 0; kb2 < 2; ++kb2) {
      bf16x8 a2[4];
#pragma unroll
      for (int mi = 0; mi < 4; ++mi) {
        const int row = wm * 64 + mi * 16 + l15;
        a2[mi] = *(const bf16x8*)&Ps[row * 72 + (((kb2 * 4 + l4) ^ psw_r) * 8)];
      }
#pragma unroll
      for (int ni = 0; ni < 4; ++ni) {
        const int d = wn * 64 + ni * 16 + l15;
        bf16x8 b2 = *(const bf16x8*)&Cb[tslot][kb2 * 8192 + d * 32 + xsw * 8];
#pragma unroll
        for (int mi = 0; mi < 4; ++mi)
          O[mi][ni] = __builtin_amdgcn_mfma_f32_16x16x32_bf16(a2[mi], b2, O[mi][ni], 0, 0, 0);
      }
    }
    __syncthreads();  // Ps reuse safe; CnT[kt+1] drained (had PV window)
  }

  // out = O * ir
#pragma unroll
  for (int mi = 0; mi < 4; ++mi)
#pragma unroll
    for (int reg = 0; reg < 4; ++reg) {
      const int row = wm * 64 + mi * 16 + l4 * 4 + reg;
      const float irv = ir[mi][reg];
#pragma unroll
      for (int ni = 0; ni < 4; ++ni) {
        const int d = wn * 64 + ni * 16 + l15;
        out[(size_t)(rb * 128 + row) * DDIM + d] = O[mi][ni][reg] * irv;
      }
    }
  // colsum partials -> global atomics (1024 addrs x 256 blocks)
  for (int j = tid; j < 1024; j += 512) atomicAdd(&colsum_g[j], csl[j]);

  // ---- last block computes the loss (ticket via cnt2; scheduling-safe, no co-residency needed)
  if (tid == 0) {
    __threadfence();
    const int old = __hip_atomic_fetch_add(cnt2, 1, __ATOMIC_ACQ_REL, __HIP_MEMORY_SCOPE_AGENT);
    lastf = (old == 255);
  }
  __syncthreads();
  if (lastf) {
    if (tid < 256) {
      float s = 0.f, q = 0.f;
#pragma unroll
      for (int j = 0; j < 4; ++j) {
        const float c = __hip_atomic_load(&colsum_g[tid + j * 256], __ATOMIC_RELAXED, __HIP_MEMORY_SCOPE_AGENT);
        s += c; q += c * c;
      }
#pragma unroll
      for (int m = 1; m < 64; m <<= 1) {
        s += __shfl_xor(s, m, 64);
        q += __shfl_xor(q, m, 64);
      }
      if (lane == 0) { sh1[tid >> 6] = s; sh2[tid >> 6] = q; }
    }
    __syncthreads();
    if (tid == 0) {
      const double S = (double)sh1[0] + sh1[1] + sh1[2] + sh1[3];  // sum of all distances (~N)
      const double Q = (double)sh2[0] + sh2[1] + sh2[2] + sh2[3];  // ||colsum||^2
      const double L = __hip_atomic_load(accL, __ATOMIC_RELAXED, __HIP_MEMORY_SCOPE_AGENT);
      const double entropy = (S * L - Q) / (double)N_ROWS;
      const double l1 = S / ((double)N_ROWS * (double)KDIM);
      out[(size_t)N_ROWS * DDIM] = (float)(1000.0 * l1 + 5e-5 * entropy);
    }
  }
}

extern "C" void kernel_launch(void* const* d_in, const int* in_sizes, int n_in,
                              void* d_out, int out_size, void* d_ws, size_t ws_size,
                              hipStream_t stream) {
  const float* x = (const float*)d_in[0];   // [8,4096,256] fp32
  const float* cb = (const float*)d_in[1];  // [1024,256] fp32
  float* out = (float*)d_out;               // recon [8388608] + loss [1]
  char* ws = (char*)d_ws;

  unsigned short* Cn  = (unsigned short*)(ws + 0);         // 524288 B (Cn64 swizzled)
  unsigned short* CnT = (unsigned short*)(ws + 524288);    // 524288 B (CnT swizzled)
  float* colsum_g     = (float*)(ws + 1048576);            // 4096 B
  float* accL         = (float*)(ws + 1052672);            // 4 B
  int* cnt2           = (int*)(ws + 1052676);              // 4 B (loss ticket)

  hipMemsetAsync(ws + 1048576, 0, 4104, stream);
  k_norm_cb<<<256, 256, 0, stream>>>(cb, Cn, CnT);
  k_all<<<256, 512, 0, stream>>>(x, Cn, CnT, colsum_g, accL, cnt2, out);
}